// Round 2
// baseline (555.674 us; speedup 1.0000x reference)
//
#include <hip/hip_runtime.h>
#include <hip/hip_bf16.h>

typedef __attribute__((ext_vector_type(8))) short bf16x8;
typedef __attribute__((ext_vector_type(4))) float f32x4;

#define HH 96
#define WWD 96
#define CIN 32
#define FF 32
#define TT 12
#define HW (HH*WWD)        // 9216
#define NPOS (8*HW)        // 73728 spatial positions (b,y,x)
#define XELEMS (8*TT*HW*CIN)   // 28,311,552
#define HELEMS (NPOS*FF)       // 2,359,296

__device__ __forceinline__ __hip_bfloat16 f2bf(float x) { return __float2bfloat16(x); }

// X fp32 -> bf16, 8 elems/thread
__global__ void cvt_x(const float* __restrict__ X, __hip_bfloat16* __restrict__ Xb) {
    int i = (blockIdx.x * 256 + threadIdx.x) * 8;
    float4 a = *(const float4*)(X + i);
    float4 b = *(const float4*)(X + i + 4);
    __hip_bfloat16 r[8] = { f2bf(a.x), f2bf(a.y), f2bf(a.z), f2bf(a.w),
                            f2bf(b.x), f2bf(b.y), f2bf(b.z), f2bf(b.w) };
    *(bf16x8*)(Xb + i) = *(bf16x8*)r;
}

// Combined transposed weights: Wt[kk][co][ci]  (kk=ky*3+kx, co 0..127, ci 0..63)
//   ci<32  -> Wx[ky,kx,ci,co]                       (multiplies x_t)
//   ci>=32 -> Wx[ky,kx,ci-32,co]+Wh[ky,kx,ci-32,co] (multiplies h_{t-1})
// since conv(h+x,Wx)+conv(h,Wh) == conv(x,Wx)+conv(h,Wx+Wh)
__global__ void prep_weights(const float* __restrict__ Wx,
                             const float* __restrict__ Wh,
                             __hip_bfloat16* __restrict__ Wt) {
    int idx = blockIdx.x * 256 + threadIdx.x;   // < 9*128*64 = 73728
    int kk = idx >> 13;
    int r  = idx & 8191;
    int co = r >> 6;
    int ci = r & 63;
    int wi = (kk * 32 + (ci & 31)) * 128 + co;
    float v = Wx[wi];
    if (ci >= 32) v += Wh[wi];
    Wt[idx] = f2bf(v);
}

// One ConvLSTM timestep. Implicit-GEMM conv (M=positions, K=3*3*64, N=128)
// with fused gate epilogue. A-fragments straight from global (predicated for
// halo), B staged in LDS with XOR bank swizzle.
__global__ __launch_bounds__(256) void lstm_step(
    const __hip_bfloat16* __restrict__ Xb,    // (8,12,96,96,32) bf16
    const __hip_bfloat16* __restrict__ Hin,   // (8,96,96,32) bf16, h_{t-1}
    const __hip_bfloat16* __restrict__ Wt,    // (9,128,64) combined
    const float* __restrict__ bias,           // (128) fp32
    float* __restrict__ Cst,                  // (73728,32) fp32 cell state
    __hip_bfloat16* __restrict__ Hout,        // (8,96,96,32) bf16, h_t
    float* __restrict__ Out,                  // (8,12,1,96,96,32) fp32
    int t)
{
    __shared__ ushort lB[128 * 64];           // 16 KB, XOR-swizzled [co][ci]

    const int tid  = threadIdx.x;
    const int lane = tid & 63;
    const int wave = tid >> 6;     // 0..3
    const int wm   = wave >> 1;    // M half (64 rows)
    const int wn   = wave & 1;     // f half (16 channels)
    const int col  = lane & 15;
    const int q    = lane >> 4;

    const int pos0 = blockIdx.x * 128;

    // per-M-tile lane coordinates (A rows: m = lane&15)
    int bb[4], yy0[4], xx0[4];
#pragma unroll
    for (int mt = 0; mt < 4; ++mt) {
        int p = pos0 + wm * 64 + mt * 16 + col;
        bb[mt]  = p / HW;
        int rem = p % HW;
        yy0[mt] = rem / WWD;
        xx0[mt] = rem % WWD;
    }

    f32x4 acc[4][4] = {};   // [mt][gate], D layout: col=lane&15, row=q*4+reg

    for (int kk = 0; kk < 9; ++kk) {
        const int ky = kk / 3, kx = kk % 3;
        __syncthreads();
        {   // stage B tile for this (ky,kx): 8192 elems, contiguous global
            const __hip_bfloat16* wsrc = Wt + kk * 8192;
#pragma unroll
            for (int rep = 0; rep < 4; ++rep) {
                int e0 = (rep * 256 + tid) * 8;
                int bco = e0 >> 6, ci0 = e0 & 63;
                *(bf16x8*)&lB[bco * 64 + (ci0 ^ ((bco & 7) * 8))] =
                    *(const bf16x8*)(wsrc + e0);
            }
        }
        __syncthreads();

        // A frags from global: x part (kc=0) and h part (kc=1)
        bf16x8 ax[4], ah[4];
#pragma unroll
        for (int mt = 0; mt < 4; ++mt) {
            int yv = yy0[mt] + ky - 1;
            int xv = xx0[mt] + kx - 1;
            bool inb = ((unsigned)yv < (unsigned)HH) & ((unsigned)xv < (unsigned)WWD);
            bf16x8 z = {0,0,0,0,0,0,0,0};
            ax[mt] = z; ah[mt] = z;
            if (inb) {
                int si = (bb[mt] * HW + yv * WWD + xv) * CIN + q * 8;  // spatial
                int xi = ((bb[mt] * TT + t) * HW + yv * WWD + xv) * CIN + q * 8;
                ax[mt] = *(const bf16x8*)(Xb + xi);
                if (t > 0)
                    ah[mt] = *(const bf16x8*)(Hin + si);
            }
        }

#pragma unroll
        for (int kc = 0; kc < 2; ++kc) {
            if (kc == 1 && t == 0) break;   // h==0 at step 0
            bf16x8 bf[4];
#pragma unroll
            for (int nt = 0; nt < 4; ++nt) {
                int co = nt * 32 + wn * 16 + col;
                bf[nt] = *(const bf16x8*)&lB[co * 64 +
                          ((kc * 32 + q * 8) ^ ((co & 7) * 8))];
            }
#pragma unroll
            for (int mt = 0; mt < 4; ++mt) {
                bf16x8 a = (kc == 0) ? ax[mt] : ah[mt];
#pragma unroll
                for (int nt = 0; nt < 4; ++nt) {
                    acc[mt][nt] = __builtin_amdgcn_mfma_f32_16x16x32_bf16(
                        a, bf[nt], acc[mt][nt], 0, 0, 0);
                }
            }
        }
    }

    // fused LSTM gate epilogue (Keras order i,f,c,o; hard_sigmoid gates)
    const int f = wn * 16 + col;
    const float bi  = bias[f];
    const float bfg = bias[32 + f];
    const float bc  = bias[64 + f];
    const float bo  = bias[96 + f];

#pragma unroll
    for (int mt = 0; mt < 4; ++mt) {
#pragma unroll
        for (int r = 0; r < 4; ++r) {
            int p  = pos0 + wm * 64 + mt * 16 + q * 4 + r;
            int b  = p / HW;
            int yx = p % HW;
            float zi = acc[mt][0][r] + bi;
            float zf = acc[mt][1][r] + bfg;
            float zc = acc[mt][2][r] + bc;
            float zo = acc[mt][3][r] + bo;
            float ig = fminf(fmaxf(0.2f * zi + 0.5f, 0.f), 1.f);
            float fg = fminf(fmaxf(0.2f * zf + 0.5f, 0.f), 1.f);
            float og = fminf(fmaxf(0.2f * zo + 0.5f, 0.f), 1.f);
            float g  = tanhf(zc);
            int cidx = p * FF + f;
            float cold = (t == 0) ? 0.f : Cst[cidx];
            float cn = fg * cold + ig * g;
            Cst[cidx] = cn;
            float h = og * tanhf(cn);
            Hout[cidx] = f2bf(h);
            Out[((b * TT + t) * HW + yx) * FF + f] = h;
        }
    }
}

extern "C" void kernel_launch(void* const* d_in, const int* in_sizes, int n_in,
                              void* d_out, int out_size, void* d_ws, size_t ws_size,
                              hipStream_t stream) {
    const float* X    = (const float*)d_in[0];
    const float* Wx   = (const float*)d_in[1];
    const float* Wh   = (const float*)d_in[2];
    const float* bias = (const float*)d_in[3];
    float* Out = (float*)d_out;

    // workspace layout (bytes):
    //   [0, 147456)            Wt   bf16 combined weights
    //   [147456, +56623104)    Xb   bf16 input copy
    //   then hA, hB bf16 (4718592 B each), Cst fp32 (9437184 B)
    char* w = (char*)d_ws;
    __hip_bfloat16* Wt = (__hip_bfloat16*)w;                 w += 9 * 128 * 64 * 2;
    __hip_bfloat16* Xb = (__hip_bfloat16*)w;                 w += (size_t)XELEMS * 2;
    __hip_bfloat16* hA = (__hip_bfloat16*)w;                 w += (size_t)HELEMS * 2;
    __hip_bfloat16* hB = (__hip_bfloat16*)w;                 w += (size_t)HELEMS * 2;
    float* Cst = (float*)w;

    cvt_x<<<XELEMS / (256 * 8), 256, 0, stream>>>(X, Xb);
    prep_weights<<<288, 256, 0, stream>>>(Wx, Wh, Wt);
    for (int t = 0; t < TT; ++t) {
        __hip_bfloat16* hin  = (t & 1) ? hB : hA;   // t=0: unused (guarded)
        __hip_bfloat16* hout = (t & 1) ? hA : hB;
        lstm_step<<<NPOS / 128, 256, 0, stream>>>(Xb, hin, Wt, bias, Cst, hout, Out, t);
    }
}

// Round 3
// 509.518 us; speedup vs baseline: 1.0906x; 1.0906x over previous
//
#include <hip/hip_runtime.h>
#include <hip/hip_bf16.h>

typedef __attribute__((ext_vector_type(8))) short bf16x8;
typedef __attribute__((ext_vector_type(4))) float f32x4;

#define HH 96
#define WWD 96
#define CIN 32
#define FF 32
#define TT 12
#define HW (HH*WWD)        // 9216
#define NPOS (8*HW)        // 73728 spatial positions (b,y,x)
#define XELEMS (8*TT*HW*CIN)   // 28,311,552
#define HELEMS (NPOS*FF)       // 2,359,296
#define BM 96              // rows per block -> 768 blocks = exactly 3/CU

__device__ __forceinline__ __hip_bfloat16 f2bf(float x) { return __float2bfloat16(x); }

// X fp32 -> bf16, 8 elems/thread
__global__ void cvt_x(const float* __restrict__ X, __hip_bfloat16* __restrict__ Xb) {
    int i = (blockIdx.x * 256 + threadIdx.x) * 8;
    float4 a = *(const float4*)(X + i);
    float4 b = *(const float4*)(X + i + 4);
    __hip_bfloat16 r[8] = { f2bf(a.x), f2bf(a.y), f2bf(a.z), f2bf(a.w),
                            f2bf(b.x), f2bf(b.y), f2bf(b.z), f2bf(b.w) };
    *(bf16x8*)(Xb + i) = *(bf16x8*)r;
}

// Combined weights stored in MFMA B-fragment-major order:
//   Wt[(((kk*2+kc)*4+q)*128 + co)*8 + j]  holds  W[kk][ci=kc*32+q*8+j][co]
//   kc=0 -> Wx (multiplies x_t);  kc=1 -> Wx+Wh (multiplies h_{t-1})
//   (conv(h+x,Wx)+conv(h,Wh) == conv(x,Wx)+conv(h,Wx+Wh))
// A wave's B-fragment load for (kk,kc,nt) is then 16 B/lane, contiguous 1 KB.
__global__ void prep_weights(const float* __restrict__ Wx,
                             const float* __restrict__ Wh,
                             __hip_bfloat16* __restrict__ Wt) {
    int idx = blockIdx.x * 256 + threadIdx.x;   // < 9*2*4*128*8 = 73728
    int j  = idx & 7;
    int co = (idx >> 3) & 127;
    int q  = (idx >> 10) & 3;
    int kc = (idx >> 12) & 1;
    int kk = idx >> 13;
    int wi = (kk * 32 + q * 8 + j) * 128 + co;
    float v = Wx[wi];
    if (kc) v += Wh[wi];
    Wt[idx] = f2bf(v);
}

// One ConvLSTM timestep. Implicit-GEMM conv (M=positions, K=3*3*64, N=128)
// with fused gate epilogue. No LDS, no barriers: A-fragments straight from
// global (predicated halo), B-fragments straight from L2-resident Wt
// (144 KB total, fragment-major). Pure load+MFMA stream.
__global__ __launch_bounds__(256, 3) void lstm_step(
    const __hip_bfloat16* __restrict__ Xb,    // (8,12,96,96,32) bf16
    const __hip_bfloat16* __restrict__ Hin,   // (8,96,96,32) bf16, h_{t-1}
    const __hip_bfloat16* __restrict__ Wt,    // (9,2,4,128,8) frag-major
    const float* __restrict__ bias,           // (128) fp32
    float* __restrict__ Cst,                  // (73728,32) fp32 cell state
    __hip_bfloat16* __restrict__ Hout,        // (8,96,96,32) bf16, h_t
    float* __restrict__ Out,                  // (8,12,1,96,96,32) fp32
    int t)
{
    const int tid  = threadIdx.x;
    const int lane = tid & 63;
    const int wave = tid >> 6;     // 0..3
    const int wm   = wave >> 1;    // M half (48 rows each)
    const int wn   = wave & 1;     // f half (16 channels)
    const int col  = lane & 15;
    const int q    = lane >> 4;

    const int pos0 = blockIdx.x * BM;

    // per-M-tile lane coordinates (A rows: m = lane&15)
    int bb[3], yy0[3], xx0[3];
#pragma unroll
    for (int mt = 0; mt < 3; ++mt) {
        int p = pos0 + wm * 48 + mt * 16 + col;
        bb[mt]  = p / HW;
        int rem = p % HW;
        yy0[mt] = rem / WWD;
        xx0[mt] = rem % WWD;
    }

    f32x4 acc[3][4] = {};   // [mt][gate], D layout: col=lane&15, row=q*4+reg

    for (int kk = 0; kk < 9; ++kk) {
        const int ky = kk / 3, kx = kk % 3;

        // A frags from global: x part (kc=0) and h part (kc=1)
        bf16x8 ax[3], ah[3];
#pragma unroll
        for (int mt = 0; mt < 3; ++mt) {
            int yv = yy0[mt] + ky - 1;
            int xv = xx0[mt] + kx - 1;
            bool inb = ((unsigned)yv < (unsigned)HH) & ((unsigned)xv < (unsigned)WWD);
            bf16x8 z = {0,0,0,0,0,0,0,0};
            ax[mt] = z; ah[mt] = z;
            if (inb) {
                int si = (bb[mt] * HW + yv * WWD + xv) * CIN + q * 8;  // spatial
                int xi = ((bb[mt] * TT + t) * HW + yv * WWD + xv) * CIN + q * 8;
                ax[mt] = *(const bf16x8*)(Xb + xi);
                if (t > 0)
                    ah[mt] = *(const bf16x8*)(Hin + si);
            }
        }

#pragma unroll
        for (int kc = 0; kc < 2; ++kc) {
            if (kc == 1 && t == 0) break;   // h==0 at step 0
            const __hip_bfloat16* bbase =
                Wt + (((kk * 2 + kc) * 4 + q) * 128 + wn * 16 + col) * 8;
            bf16x8 bf[4];
#pragma unroll
            for (int nt = 0; nt < 4; ++nt)
                bf[nt] = *(const bf16x8*)(bbase + nt * 256);
#pragma unroll
            for (int mt = 0; mt < 3; ++mt) {
                bf16x8 a = (kc == 0) ? ax[mt] : ah[mt];
#pragma unroll
                for (int nt = 0; nt < 4; ++nt) {
                    acc[mt][nt] = __builtin_amdgcn_mfma_f32_16x16x32_bf16(
                        a, bf[nt], acc[mt][nt], 0, 0, 0);
                }
            }
        }
    }

    // fused LSTM gate epilogue (Keras order i,f,c,o; hard_sigmoid gates)
    const int f = wn * 16 + col;
    const float bi  = bias[f];
    const float bfg = bias[32 + f];
    const float bc  = bias[64 + f];
    const float bo  = bias[96 + f];

#pragma unroll
    for (int mt = 0; mt < 3; ++mt) {
#pragma unroll
        for (int r = 0; r < 4; ++r) {
            int p  = pos0 + wm * 48 + mt * 16 + q * 4 + r;
            int b  = p / HW;
            int yx = p % HW;
            float zi = acc[mt][0][r] + bi;
            float zf = acc[mt][1][r] + bfg;
            float zc = acc[mt][2][r] + bc;
            float zo = acc[mt][3][r] + bo;
            float ig = fminf(fmaxf(0.2f * zi + 0.5f, 0.f), 1.f);
            float fg = fminf(fmaxf(0.2f * zf + 0.5f, 0.f), 1.f);
            float og = fminf(fmaxf(0.2f * zo + 0.5f, 0.f), 1.f);
            float g  = tanhf(zc);
            int cidx = p * FF + f;
            float cold = (t == 0) ? 0.f : Cst[cidx];
            float cn = fg * cold + ig * g;
            Cst[cidx] = cn;
            float h = og * tanhf(cn);
            Hout[cidx] = f2bf(h);
            Out[((b * TT + t) * HW + yx) * FF + f] = h;
        }
    }
}

extern "C" void kernel_launch(void* const* d_in, const int* in_sizes, int n_in,
                              void* d_out, int out_size, void* d_ws, size_t ws_size,
                              hipStream_t stream) {
    const float* X    = (const float*)d_in[0];
    const float* Wx   = (const float*)d_in[1];
    const float* Wh   = (const float*)d_in[2];
    const float* bias = (const float*)d_in[3];
    float* Out = (float*)d_out;

    // workspace layout: Wt bf16 (147456 B) | Xb bf16 | hA, hB bf16 | Cst fp32
    char* w = (char*)d_ws;
    __hip_bfloat16* Wt = (__hip_bfloat16*)w;                 w += 9 * 2 * 4 * 128 * 8 * 2;
    __hip_bfloat16* Xb = (__hip_bfloat16*)w;                 w += (size_t)XELEMS * 2;
    __hip_bfloat16* hA = (__hip_bfloat16*)w;                 w += (size_t)HELEMS * 2;
    __hip_bfloat16* hB = (__hip_bfloat16*)w;                 w += (size_t)HELEMS * 2;
    float* Cst = (float*)w;

    cvt_x<<<XELEMS / (256 * 8), 256, 0, stream>>>(X, Xb);
    prep_weights<<<288, 256, 0, stream>>>(Wx, Wh, Wt);
    for (int t = 0; t < TT; ++t) {
        __hip_bfloat16* hin  = (t & 1) ? hB : hA;   // t=0: unused (guarded)
        __hip_bfloat16* hout = (t & 1) ? hA : hB;
        lstm_step<<<NPOS / BM, 256, 0, stream>>>(Xb, hin, Wt, bias, Cst, hout, Out, t);
    }
}